// Round 5
// baseline (2620.545 us; speedup 1.0000x reference)
//
#include <hip/hip_runtime.h>

// DA-RNN decoder: B=512, T=128, E=256, D=256, OUT=1.
// One persistent kernel, 256 blocks x 1024 threads, NB=2 batch rows/block.
// WAVE SPECIALIZATION: waves 0-7 (Q-group) do q-GEMM -> scores -> softmax ->
// LSTM update; waves 8-15 (G-group) do the gates GEMM (h@Whh.T) split in two
// K-chunks so the 768 KB/step L2 weight stream runs continuously across the
// whole step. 3 barriers/step. h/c packed f16 in LDS; c fp32 in registers.

#define BB 512
#define TT 128
#define EE 256
#define DD 256
#define NB 2
#define NTHR 1024

typedef _Float16 h2 __attribute__((ext_vector_type(2)));
typedef _Float16 h8 __attribute__((ext_vector_type(8)));

#if defined(__has_builtin)
#if __has_builtin(__builtin_amdgcn_fdot2)
#define HAS_FDOT2 1
#endif
#endif

#ifdef HAS_FDOT2
#define FDOT2(a, b, c) __builtin_amdgcn_fdot2(__builtin_bit_cast(h2, (a)), __builtin_bit_cast(h2, (b)), (c), false)
#else
static __device__ __forceinline__ float FDOT2(unsigned int a, unsigned int b, float c) {
    h2 x = __builtin_bit_cast(h2, a), y = __builtin_bit_cast(h2, b);
    return c + (float)x[0] * (float)y[0] + (float)x[1] * (float)y[1];
}
#endif

static __device__ __forceinline__ float dot8u4(uint4 w, uint4 h, float acc) {
    acc = FDOT2(w.x, h.x, acc);
    acc = FDOT2(w.y, h.y, acc);
    acc = FDOT2(w.z, h.z, acc);
    acc = FDOT2(w.w, h.w, acc);
    return acc;
}
static __device__ __forceinline__ unsigned int pkh(float a, float b) {
    union { _Float16 h; unsigned short s; } ua, ub;
    ua.h = (_Float16)a; ub.h = (_Float16)b;
    return (unsigned int)ua.s | ((unsigned int)ub.s << 16);
}
__device__ __forceinline__ float ftanh(float x) {
    return 1.f - 2.f * __builtin_amdgcn_rcpf(__expf(2.f * x) + 1.f);
}
__device__ __forceinline__ float fsig(float x) {
    return __builtin_amdgcn_rcpf(1.f + __expf(-x));
}

// Pack weights to f16 in the exact load order of k_main.
// aW1h[(g*256+f)*8+j] = aW1[g*8+j][f]      (g = kh*32+i < 64, k=g*8+j < 512)
// WhhH[(i*1024+jj)*8+m] = Whh[jj][i*8+m]   (i<32)
__global__ __launch_bounds__(256) void k_pack(const float* __restrict__ aW1,
                                              const float* __restrict__ Whh,
                                              const float* __restrict__ bih,
                                              const float* __restrict__ bhh,
                                              _Float16* __restrict__ aW1h,
                                              _Float16* __restrict__ WhhH,
                                              float* __restrict__ bias) {
    int bid = blockIdx.x, tid = threadIdx.x;
    if (bid < 512) {
        int o = bid * 256 + tid;                 // < 131072
        int g = o >> 11, f = (o >> 3) & 255, j = o & 7;
        aW1h[o] = (_Float16)aW1[(g * 8 + j) * EE + f];
    } else if (bid < 1536) {
        int o = (bid - 512) * 256 + tid;         // < 262144
        int i = o >> 13, jj = (o >> 3) & 1023, m = o & 7;
        WhhH[o] = (_Float16)Whh[jj * DD + i * 8 + m];
    } else {
        int j = (bid - 1536) * 256 + tid;        // < 1024
        bias[j] = bih[j] + bhh[j];
    }
}

// ep[n][f] = f16( sum_e ie[n][e]*aW1[512+e][f] )
// epilogue: iefc[n] = dot(ie[n], fcW[0:256]); ieff[n] = dot(ie[n], ffW[256:512])
__global__ __launch_bounds__(256) void k_encproj(const float* __restrict__ ie,
                                                 const float* __restrict__ aW1,
                                                 const float* __restrict__ fcW,
                                                 const float* __restrict__ ffW,
                                                 _Float16* __restrict__ ep,
                                                 float* __restrict__ iefc,
                                                 float* __restrict__ ieff) {
    __shared__ float a[32][EE];
    int row0 = blockIdx.x * 32;
    int tid = threadIdx.x;
    for (int r = 0; r < 32; ++r)
        a[r][tid] = ie[(size_t)(row0 + r) * EE + tid];
    __syncthreads();
    float acc[32];
    #pragma unroll
    for (int r = 0; r < 32; ++r) acc[r] = 0.f;
    const float* wenc = aW1 + 512 * EE;
    for (int e = 0; e < EE; e += 4) {
        float w0 = wenc[(e + 0) * EE + tid];
        float w1 = wenc[(e + 1) * EE + tid];
        float w2 = wenc[(e + 2) * EE + tid];
        float w3 = wenc[(e + 3) * EE + tid];
        #pragma unroll
        for (int r = 0; r < 32; ++r) {
            float4 av = *(const float4*)&a[r][e];
            acc[r] += av.x * w0 + av.y * w1 + av.z * w2 + av.w * w3;
        }
    }
    for (int r = 0; r < 32; ++r)
        ep[(size_t)(row0 + r) * EE + tid] = (_Float16)acc[r];

    int wave = tid >> 6, lane = tid & 63;
    float4 f1 = *(const float4*)&fcW[lane * 4];
    float4 f2 = *(const float4*)&ffW[EE + lane * 4];
    #pragma unroll
    for (int rr = 0; rr < 8; ++rr) {
        int r = wave * 8 + rr;
        float4 v = *(const float4*)&a[r][lane * 4];
        float p1 = v.x * f1.x + v.y * f1.y + v.z * f1.z + v.w * f1.w;
        float p2 = v.x * f2.x + v.y * f2.y + v.z * f2.z + v.w * f2.w;
        #pragma unroll
        for (int off = 1; off <= 32; off <<= 1) {
            p1 += __shfl_xor(p1, off);
            p2 += __shfl_xor(p2, off);
        }
        if (lane == 0) {
            iefc[row0 + r] = p1;
            ieff[row0 + r] = p2;
        }
    }
}

__global__ __launch_bounds__(NTHR) void k_main(
    const _Float16* __restrict__ ep, const float* __restrict__ yh,
    const _Float16* __restrict__ aW1h, const _Float16* __restrict__ WhhH,
    const float* __restrict__ bias_, const float* __restrict__ ab1,
    const float* __restrict__ aW2, const float* __restrict__ Wih,
    const float* __restrict__ fcW, const float* __restrict__ fcb,
    const float* __restrict__ ffW, const float* __restrict__ ffb,
    const float* __restrict__ iefc, const float* __restrict__ ieff,
    float* __restrict__ out) {
    __shared__ unsigned int s_hc16[NB][2][128];  // [b][0=h,1=c], f16 pairs
    __shared__ float s_qp[2][NB][EE];            // [kh][b][32*(f&7)+(f>>3)]
    __shared__ float s_sc[NB * TT];
    __shared__ float s_g[NB][4 * DD];            // h.Whh + bias (yt added later)
    __shared__ float s_wih[4 * DD];
    __shared__ float s_iefc[NB][TT];
    __shared__ float s_ieff[NB][TT];
    __shared__ float s_yh[NB][TT];

    const int tid = threadIdx.x;
    const int wave = tid >> 6, lane = tid & 63;
    const int b0 = blockIdx.x * NB;
    const bool isQ = tid < 512;

    for (int i = tid; i < 4 * DD; i += NTHR) s_wih[i] = Wih[i];
    for (int i = tid; i < NB * TT; i += NTHR) {
        int b = i >> 7, t = i & 127;
        s_iefc[b][t] = iefc[(b0 + b) * TT + t];
        s_ieff[b][t] = ieff[(b0 + b) * TT + t];
        s_yh[b][t]   = yh[(size_t)(b0 + b) * TT + t];
    }
    for (int i = tid; i < NB * 2 * 128; i += NTHR) (&s_hc16[0][0][0])[i] = 0u;

    // ----- Q-group mapping (waves 0-7): q-GEMM thread = (qkh, qf) -----
    const int qf = tid & 255, qkh = (tid >> 8) & 1;
    const float qinit = qkh ? 0.f : ab1[qf];
    const uint4* qW = (const uint4*)aW1h + ((size_t)(qkh * 32) * 256 + qf);
    const int qperm = 32 * (qf & 7) + (qf >> 3);

    // ----- G-group mapping (waves 8-15): gate rows gt and gt+512 -----
    const int gt = tid & 511;
    const uint4* wPa = (const uint4*)WhhH + gt;
    const uint4* wPb = (const uint4*)WhhH + gt + 512;
    const float bias_a = bias_[gt], bias_b = bias_[gt + 512];

    // ----- scores mapping (Q-group) -----
    const int l5 = lane & 31;
    const int rsub = (wave & 7) * 2 + (lane >> 5);   // [0,16)
    const int e0 = l5 * 8;
    float tw2[8]; float sw2 = 0.f;
    #pragma unroll
    for (int j = 0; j < 8; ++j) { float w = aW2[e0 + j]; tw2[j] = 2.f * w; sw2 += w; }

    const float fcw256 = fcW[256], fcb0 = fcb[0], ffb0 = ffb[0];
    float c_reg = 0.f;                               // fp32 cell (Q-group, d=tid&255)
    float ofs_reg = 0.f;
    float g_a0 = 0.f, g_a1 = 0.f, g_b0 = 0.f, g_b1 = 0.f;  // G accumulators

    __syncthreads();

    for (int t = 0; t < TT; ++t) {
        // ========== P1: Q: q-GEMM (both b) ; G: gates K-chunk 1 ==========
        if (isQ) {
            float qa0 = qinit, qa1 = qinit;
            #pragma unroll 8
            for (int i = 0; i < 32; ++i) {
                uint4 wv = qW[(size_t)i * 256];
                uint4 h0 = *(const uint4*)&s_hc16[0][qkh][i * 4];
                uint4 h1 = *(const uint4*)&s_hc16[1][qkh][i * 4];
                qa0 = dot8u4(wv, h0, qa0);
                qa1 = dot8u4(wv, h1, qa1);
            }
            s_qp[qkh][0][qperm] = qa0;
            s_qp[qkh][1][qperm] = qa1;
        } else {
            g_a0 = bias_a; g_a1 = bias_a; g_b0 = bias_b; g_b1 = bias_b;
            #pragma unroll 8
            for (int i = 0; i < 16; ++i) {
                uint4 wa = wPa[(size_t)i * 1024];
                uint4 wb = wPb[(size_t)i * 1024];
                uint4 h0 = *(const uint4*)&s_hc16[0][0][i * 4];
                uint4 h1 = *(const uint4*)&s_hc16[1][0][i * 4];
                g_a0 = dot8u4(wa, h0, g_a0);
                g_a1 = dot8u4(wa, h1, g_a1);
                g_b0 = dot8u4(wb, h0, g_b0);
                g_b1 = dot8u4(wb, h1, g_b1);
            }
        }
        __syncthreads();

        // ========== P2: Q: scores ; G: gates K-chunk 2 + write ==========
        if (isQ) {
            #pragma unroll
            for (int b = 0; b < NB; ++b) {
                float qs[8];
                #pragma unroll
                for (int j = 0; j < 8; ++j)
                    qs[j] = 2.f * (s_qp[0][b][l5 + 32 * j] + s_qp[1][b][l5 + 32 * j]);
                const _Float16* eph = ep + (size_t)(b0 + b) * TT * EE + e0;
                #pragma unroll
                for (int sw = 0; sw < 8; ++sw) {
                    int tt2 = sw * 16 + rsub;
                    h8 xv = *(const h8*)(eph + (size_t)tt2 * EE);
                    float s = sw2;
                    #pragma unroll
                    for (int j = 0; j < 8; ++j) {
                        float e = __expf(__fmaf_rn((float)xv[j], 2.f, qs[j]));
                        s = __fmaf_rn(-tw2[j], __builtin_amdgcn_rcpf(e + 1.f), s);
                    }
                    #pragma unroll
                    for (int off = 1; off <= 16; off <<= 1) s += __shfl_xor(s, off);
                    if (l5 == 0) s_sc[b * TT + tt2] = s;
                }
            }
        } else {
            #pragma unroll 8
            for (int i = 16; i < 32; ++i) {
                uint4 wa = wPa[(size_t)i * 1024];
                uint4 wb = wPb[(size_t)i * 1024];
                uint4 h0 = *(const uint4*)&s_hc16[0][0][i * 4];
                uint4 h1 = *(const uint4*)&s_hc16[1][0][i * 4];
                g_a0 = dot8u4(wa, h0, g_a0);
                g_a1 = dot8u4(wa, h1, g_a1);
                g_b0 = dot8u4(wb, h0, g_b0);
                g_b1 = dot8u4(wb, h1, g_b1);
            }
            s_g[0][gt]       = g_a0;
            s_g[1][gt]       = g_a1;
            s_g[0][gt + 512] = g_b0;
            s_g[1][gt + 512] = g_b1;
        }
        __syncthreads();

        // ========== P3: Q-group: per-wave softmax + yt + LSTM update ==========
        if (isQ) {
            int b = tid >> 8, d = tid & 255;
            float v0 = s_sc[b * TT + lane], v1 = s_sc[b * TT + 64 + lane];
            float m = fmaxf(v0, v1);
            #pragma unroll
            for (int off = 1; off <= 32; off <<= 1) m = fmaxf(m, __shfl_xor(m, off));
            float x0 = __expf(v0 - m), x1 = __expf(v1 - m);
            float ss = x0 + x1;
            #pragma unroll
            for (int off = 1; off <= 32; off <<= 1) ss += __shfl_xor(ss, off);
            float inv = __builtin_amdgcn_rcpf(ss);
            float a0 = x0 * inv, a1 = x1 * inv;
            float p = a0 * s_iefc[b][lane] + a1 * s_iefc[b][64 + lane];
            #pragma unroll
            for (int off = 1; off <= 32; off <<= 1) p += __shfl_xor(p, off);
            float yt = p + s_yh[b][t] * fcw256 + fcb0;
            if (t == TT - 1) {
                float pf = a0 * s_ieff[b][lane] + a1 * s_ieff[b][64 + lane];
                #pragma unroll
                for (int off = 1; off <= 32; off <<= 1) pf += __shfl_xor(pf, off);
                ofs_reg = pf;
            }
            float gi = s_g[b][d]          + yt * s_wih[d];
            float gf = s_g[b][DD + d]     + yt * s_wih[DD + d];
            float gg = s_g[b][2 * DD + d] + yt * s_wih[2 * DD + d];
            float go = s_g[b][3 * DD + d] + yt * s_wih[3 * DD + d];
            float c2 = fsig(gf) * c_reg + fsig(gi) * ftanh(gg);
            c_reg = c2;
            float hn = fsig(go) * ftanh(c2);
            float hO = __shfl_xor(hn, 1);
            float cO = __shfl_xor(c2, 1);
            if (!(d & 1)) {
                s_hc16[b][0][d >> 1] = pkh(hn, hO);
                s_hc16[b][1][d >> 1] = pkh(c2, cO);
            }
        }
        __syncthreads();
    }

    // ---------- final: out[b] = h.ffW[:256] + (attn_last . ieff) + ffb ----------
    if (wave == 0 || wave == 4) {
        int b = wave >> 2;
        unsigned int p0 = s_hc16[b][0][lane * 2];
        unsigned int p1 = s_hc16[b][0][lane * 2 + 1];
        h2 ha = __builtin_bit_cast(h2, p0), hb = __builtin_bit_cast(h2, p1);
        float4 w = *(const float4*)&ffW[lane * 4];
        float p = (float)ha[0] * w.x + (float)ha[1] * w.y
                + (float)hb[0] * w.z + (float)hb[1] * w.w;
        #pragma unroll
        for (int off = 1; off <= 32; off <<= 1) p += __shfl_xor(p, off);
        if (lane == 0) out[b0 + b] = p + ofs_reg + ffb0;
    }
}

extern "C" void kernel_launch(void* const* d_in, const int* in_sizes, int n_in,
                              void* d_out, int out_size, void* d_ws, size_t ws_size,
                              hipStream_t stream) {
    const float* ie  = (const float*)d_in[0];   // [B,T,E]
    const float* yh  = (const float*)d_in[1];   // [B,T,1]
    const float* aW1 = (const float*)d_in[2];   // [768,256]
    const float* ab1 = (const float*)d_in[3];   // [256]
    const float* aW2 = (const float*)d_in[4];   // [256,1]
    // d_in[5] = ab2: additive constant inside softmax -> invariant, unused
    const float* Wih = (const float*)d_in[6];   // [1024,1]
    const float* Whh = (const float*)d_in[7];   // [1024,256]
    const float* bih = (const float*)d_in[8];   // [1024]
    const float* bhh = (const float*)d_in[9];   // [1024]
    const float* fcW = (const float*)d_in[10];  // [1,257]
    const float* fcb = (const float*)d_in[11];  // [1]
    const float* ffW = (const float*)d_in[12];  // [1,512]
    const float* ffb = (const float*)d_in[13];  // [1]
    float* out = (float*)d_out;

    // workspace layout
    _Float16* ep   = (_Float16*)d_ws;                        // 16,777,216 f16 = 32 MiB
    _Float16* aW1h = ep + (size_t)BB * TT * EE;              // 131072 f16
    _Float16* WhhH = aW1h + 512 * EE;                        // 262144 f16
    float* bias = (float*)(WhhH + 262144);                   // 1024 f32
    float* iefc = bias + 1024;                               // 65536 f32
    float* ieff = iefc + BB * TT;                            // 65536 f32

    k_pack<<<1540, 256, 0, stream>>>(aW1, Whh, bih, bhh, aW1h, WhhH, bias);
    k_encproj<<<2048, 256, 0, stream>>>(ie, aW1, fcW, ffW, ep, iefc, ieff);
    k_main<<<BB / NB, NTHR, 0, stream>>>(ep, yh, aW1h, WhhH, bias, ab1, aW2,
                                         Wih, fcW, fcb, ffW, ffb, iefc, ieff, out);
}

// Round 6
// 2026.003 us; speedup vs baseline: 1.2935x; 1.2935x over previous
//
#include <hip/hip_runtime.h>

// DA-RNN decoder: B=512, T=128, E=256, D=256, OUT=1.
// One persistent kernel, 256 blocks x 1024 threads (lockstep phases, no wave
// specialization - R5 showed it breaks L3 residency). NB=2 batch rows/block.
// NEW: the block's ep slice (2 rows x 128 x 256 f16 = 128 KB) is staged in
// LDS ONCE before the t-loop -> zero per-step ep traffic; the only per-step
// global stream is the weights (768 KB/CU), which stay L2-resident.
// h/c packed f16 in LDS; c fp32 in registers. GEMMs via v_dot2_f32_f16.

#define BB 512
#define TT 128
#define EE 256
#define DD 256
#define NB 2
#define NTHR 1024

typedef _Float16 h2 __attribute__((ext_vector_type(2)));
typedef _Float16 h8 __attribute__((ext_vector_type(8)));

#if defined(__has_builtin)
#if __has_builtin(__builtin_amdgcn_fdot2)
#define HAS_FDOT2 1
#endif
#endif

#ifdef HAS_FDOT2
#define FDOT2(a, b, c) __builtin_amdgcn_fdot2(__builtin_bit_cast(h2, (a)), __builtin_bit_cast(h2, (b)), (c), false)
#else
static __device__ __forceinline__ float FDOT2(unsigned int a, unsigned int b, float c) {
    h2 x = __builtin_bit_cast(h2, a), y = __builtin_bit_cast(h2, b);
    return c + (float)x[0] * (float)y[0] + (float)x[1] * (float)y[1];
}
#endif

static __device__ __forceinline__ float dot8u4(uint4 w, uint4 h, float acc) {
    acc = FDOT2(w.x, h.x, acc);
    acc = FDOT2(w.y, h.y, acc);
    acc = FDOT2(w.z, h.z, acc);
    acc = FDOT2(w.w, h.w, acc);
    return acc;
}
static __device__ __forceinline__ unsigned int pkh(float a, float b) {
    union { _Float16 h; unsigned short s; } ua, ub;
    ua.h = (_Float16)a; ub.h = (_Float16)b;
    return (unsigned int)ua.s | ((unsigned int)ub.s << 16);
}
__device__ __forceinline__ float ftanh(float x) {
    return 1.f - 2.f * __builtin_amdgcn_rcpf(__expf(2.f * x) + 1.f);
}
__device__ __forceinline__ float fsig(float x) {
    return __builtin_amdgcn_rcpf(1.f + __expf(-x));
}

// Pack weights to f16 in the exact load order of k_main.
// aW1h[(g*256+f)*8+j] = aW1[g*8+j][f]      (g = kh*32+i < 64, k=g*8+j < 512)
// WhhH[(i*1024+jj)*8+m] = Whh[jj][i*8+m]   (i<32)
__global__ __launch_bounds__(256) void k_pack(const float* __restrict__ aW1,
                                              const float* __restrict__ Whh,
                                              const float* __restrict__ bih,
                                              const float* __restrict__ bhh,
                                              _Float16* __restrict__ aW1h,
                                              _Float16* __restrict__ WhhH,
                                              float* __restrict__ bias) {
    int bid = blockIdx.x, tid = threadIdx.x;
    if (bid < 512) {
        int o = bid * 256 + tid;                 // < 131072
        int g = o >> 11, f = (o >> 3) & 255, j = o & 7;
        aW1h[o] = (_Float16)aW1[(g * 8 + j) * EE + f];
    } else if (bid < 1536) {
        int o = (bid - 512) * 256 + tid;         // < 262144
        int i = o >> 13, jj = (o >> 3) & 1023, m = o & 7;
        WhhH[o] = (_Float16)Whh[jj * DD + i * 8 + m];
    } else {
        int j = (bid - 1536) * 256 + tid;        // < 1024
        bias[j] = bih[j] + bhh[j];
    }
}

// ep[n][f] = f16( sum_e ie[n][e]*aW1[512+e][f] )
// epilogue: iefc[n] = dot(ie[n], fcW[0:256]); ieff[n] = dot(ie[n], ffW[256:512])
__global__ __launch_bounds__(256) void k_encproj(const float* __restrict__ ie,
                                                 const float* __restrict__ aW1,
                                                 const float* __restrict__ fcW,
                                                 const float* __restrict__ ffW,
                                                 _Float16* __restrict__ ep,
                                                 float* __restrict__ iefc,
                                                 float* __restrict__ ieff) {
    __shared__ float a[32][EE];
    int row0 = blockIdx.x * 32;
    int tid = threadIdx.x;
    for (int r = 0; r < 32; ++r)
        a[r][tid] = ie[(size_t)(row0 + r) * EE + tid];
    __syncthreads();
    float acc[32];
    #pragma unroll
    for (int r = 0; r < 32; ++r) acc[r] = 0.f;
    const float* wenc = aW1 + 512 * EE;
    for (int e = 0; e < EE; e += 4) {
        float w0 = wenc[(e + 0) * EE + tid];
        float w1 = wenc[(e + 1) * EE + tid];
        float w2 = wenc[(e + 2) * EE + tid];
        float w3 = wenc[(e + 3) * EE + tid];
        #pragma unroll
        for (int r = 0; r < 32; ++r) {
            float4 av = *(const float4*)&a[r][e];
            acc[r] += av.x * w0 + av.y * w1 + av.z * w2 + av.w * w3;
        }
    }
    for (int r = 0; r < 32; ++r)
        ep[(size_t)(row0 + r) * EE + tid] = (_Float16)acc[r];

    int wave = tid >> 6, lane = tid & 63;
    float4 f1 = *(const float4*)&fcW[lane * 4];
    float4 f2 = *(const float4*)&ffW[EE + lane * 4];
    #pragma unroll
    for (int rr = 0; rr < 8; ++rr) {
        int r = wave * 8 + rr;
        float4 v = *(const float4*)&a[r][lane * 4];
        float p1 = v.x * f1.x + v.y * f1.y + v.z * f1.z + v.w * f1.w;
        float p2 = v.x * f2.x + v.y * f2.y + v.z * f2.z + v.w * f2.w;
        #pragma unroll
        for (int off = 1; off <= 32; off <<= 1) {
            p1 += __shfl_xor(p1, off);
            p2 += __shfl_xor(p2, off);
        }
        if (lane == 0) {
            iefc[row0 + r] = p1;
            ieff[row0 + r] = p2;
        }
    }
}

__global__ __launch_bounds__(NTHR) void k_main(
    const _Float16* __restrict__ ep, const float* __restrict__ yh,
    const _Float16* __restrict__ aW1h, const _Float16* __restrict__ WhhH,
    const float* __restrict__ bias_, const float* __restrict__ ab1,
    const float* __restrict__ aW2, const float* __restrict__ Wih,
    const float* __restrict__ fcW, const float* __restrict__ fcb,
    const float* __restrict__ ffW, const float* __restrict__ ffb,
    const float* __restrict__ iefc, const float* __restrict__ ieff,
    float* __restrict__ out) {
    __shared__ _Float16 s_ep[NB * TT * EE];      // 128 KB: block's ep slice
    __shared__ unsigned int s_hc16[NB][2][128];  // [b][0=h,1=c], f16 pairs
    __shared__ float s_qp[2][NB][EE];            // [kh][b][32*(f&7)+(f>>3)]
    __shared__ float s_sc[NB * TT];
    __shared__ float s_g[NB][4 * DD];            // h.Whh + bias (yt added later)
    __shared__ float s_wih[4 * DD];
    __shared__ float s_iefc[NB][TT];
    __shared__ float s_ieff[NB][TT];
    __shared__ float s_yh[NB][TT];
    __shared__ float s_yt[NB];
    __shared__ float s_ofs[NB];

    const int tid = threadIdx.x;
    const int wave = tid >> 6, lane = tid & 63;
    const int b0 = blockIdx.x * NB;

    // one-time: stage this block's ep slice into LDS (contiguous 128 KB)
    {
        const uint4* src = (const uint4*)(ep + (size_t)b0 * TT * EE);
        uint4* dst = (uint4*)s_ep;
        #pragma unroll
        for (int i = 0; i < (NB * TT * EE) / 8 / NTHR; ++i)
            dst[tid + i * NTHR] = src[tid + i * NTHR];
    }
    for (int i = tid; i < 4 * DD; i += NTHR) s_wih[i] = Wih[i];
    for (int i = tid; i < NB * TT; i += NTHR) {
        int b = i >> 7, t = i & 127;
        s_iefc[b][t] = iefc[(b0 + b) * TT + t];
        s_ieff[b][t] = ieff[(b0 + b) * TT + t];
        s_yh[b][t]   = yh[(size_t)(b0 + b) * TT + t];
    }
    for (int i = tid; i < NB * 2 * 128; i += NTHR) (&s_hc16[0][0][0])[i] = 0u;

    // ----- q mapping: thread = (qb, qkh, qf) -----
    const int qf = tid & 255, qkh = (tid >> 8) & 1, qb = tid >> 9;
    const float qinit = qkh ? 0.f : ab1[qf];
    const uint4* qW = (const uint4*)aW1h + ((size_t)(qkh * 32) * 256 + qf);
    const int qperm = 32 * (qf & 7) + (qf >> 3);

    // ----- gates mapping: thread = gate row j -----
    const uint4* wP = (const uint4*)WhhH + tid;
    const float biasv = bias_[tid];

    // ----- scores mapping -----
    const int l5 = lane & 31;
    const int rsub = wave * 2 + (lane >> 5);     // [0,32)
    const int e0 = l5 * 8;
    float tw2[8]; float sw2 = 0.f;
    #pragma unroll
    for (int j = 0; j < 8; ++j) { float w = aW2[e0 + j]; tw2[j] = 2.f * w; sw2 += w; }

    const float fcw256 = fcW[256], fcb0 = fcb[0], ffb0 = ffb[0];
    float c_reg = 0.f;                           // fp32 cell state (tid<512)

    __syncthreads();

    for (int t = 0; t < TT; ++t) {
        // ---------- A: q = [h;c]@aW1 (+ab1)  AND  g = h@Whh.T + bias ----------
        float qa = qinit;
        float g0 = biasv, g1 = biasv;
        #pragma unroll 8
        for (int i = 0; i < 32; ++i) {
            uint4 wv = qW[(size_t)i * 256];
            uint4 hv = *(const uint4*)&s_hc16[qb][qkh][i * 4];
            qa = dot8u4(wv, hv, qa);
            uint4 gw = wP[(size_t)i * 1024];
            uint4 h0 = *(const uint4*)&s_hc16[0][0][i * 4];
            uint4 h1 = *(const uint4*)&s_hc16[1][0][i * 4];
            g0 = dot8u4(gw, h0, g0);
            g1 = dot8u4(gw, h1, g1);
        }
        s_qp[qkh][qb][qperm] = qa;
        s_g[0][tid] = g0;
        s_g[1][tid] = g1;
        __syncthreads();

        // ---------- B: scores s[b][t'] = sum_f w2[f]*tanh(qp0+qp1+ep) ----------
        #pragma unroll
        for (int b = 0; b < NB; ++b) {
            float qs[8];
            #pragma unroll
            for (int j = 0; j < 8; ++j)
                qs[j] = 2.f * (s_qp[0][b][l5 + 32 * j] + s_qp[1][b][l5 + 32 * j]);
            const _Float16* eph = s_ep + b * TT * EE + e0;
            #pragma unroll
            for (int sw = 0; sw < 4; ++sw) {
                int tt2 = sw * 32 + rsub;
                h8 xv = *(const h8*)(eph + tt2 * EE);
                float s = sw2;
                #pragma unroll
                for (int j = 0; j < 8; ++j) {
                    float e = __expf(__fmaf_rn((float)xv[j], 2.f, qs[j]));
                    s = __fmaf_rn(-tw2[j], __builtin_amdgcn_rcpf(e + 1.f), s);
                }
                #pragma unroll
                for (int off = 1; off <= 16; off <<= 1) s += __shfl_xor(s, off);
                if (l5 == 0) s_sc[b * TT + tt2] = s;
            }
        }
        __syncthreads();

        // ---------- C: softmax + y_tilde (wave 0 -> b=0, wave 8 -> b=1) ----------
        if ((wave & 7) == 0) {
            int b = wave >> 3;
            float v0 = s_sc[b * TT + lane], v1 = s_sc[b * TT + 64 + lane];
            float m = fmaxf(v0, v1);
            #pragma unroll
            for (int off = 1; off <= 32; off <<= 1) m = fmaxf(m, __shfl_xor(m, off));
            float x0 = __expf(v0 - m), x1 = __expf(v1 - m);
            float ss = x0 + x1;
            #pragma unroll
            for (int off = 1; off <= 32; off <<= 1) ss += __shfl_xor(ss, off);
            float inv = __builtin_amdgcn_rcpf(ss);
            float a0 = x0 * inv, a1 = x1 * inv;
            float p  = a0 * s_iefc[b][lane] + a1 * s_iefc[b][64 + lane];
            float pf = (t == TT - 1) ? (a0 * s_ieff[b][lane] + a1 * s_ieff[b][64 + lane]) : 0.f;
            #pragma unroll
            for (int off = 1; off <= 32; off <<= 1) {
                p  += __shfl_xor(p, off);
                pf += __shfl_xor(pf, off);
            }
            if (lane == 0) {
                s_yt[b] = p + s_yh[b][t] * fcw256 + fcb0;
                if (t == TT - 1) s_ofs[b] = pf;
            }
        }
        __syncthreads();

        // ---------- D: apply yt + LSTM update (tid<512), pack h/c to f16 ----------
        if (tid < NB * DD) {
            int b = tid >> 8, d = tid & 255;
            float yt = s_yt[b];
            float gi = s_g[b][d]          + yt * s_wih[d];
            float gf = s_g[b][DD + d]     + yt * s_wih[DD + d];
            float gg = s_g[b][2 * DD + d] + yt * s_wih[2 * DD + d];
            float go = s_g[b][3 * DD + d] + yt * s_wih[3 * DD + d];
            float c2 = fsig(gf) * c_reg + fsig(gi) * ftanh(gg);
            c_reg = c2;
            float hn = fsig(go) * ftanh(c2);
            float hO = __shfl_xor(hn, 1);
            float cO = __shfl_xor(c2, 1);
            if (!(d & 1)) {
                s_hc16[b][0][d >> 1] = pkh(hn, hO);
                s_hc16[b][1][d >> 1] = pkh(c2, cO);
            }
        }
        __syncthreads();
    }

    // ---------- final: out[b] = h.ffW[:256] + (attn_last . ieff) + ffb ----------
    if ((wave & 7) == 0) {
        int b = wave >> 3;
        unsigned int p0 = s_hc16[b][0][lane * 2];
        unsigned int p1 = s_hc16[b][0][lane * 2 + 1];
        h2 ha = __builtin_bit_cast(h2, p0), hb = __builtin_bit_cast(h2, p1);
        float4 w = *(const float4*)&ffW[lane * 4];
        float p = (float)ha[0] * w.x + (float)ha[1] * w.y
                + (float)hb[0] * w.z + (float)hb[1] * w.w;
        #pragma unroll
        for (int off = 1; off <= 32; off <<= 1) p += __shfl_xor(p, off);
        if (lane == 0) out[b0 + b] = p + s_ofs[b] + ffb0;
    }
}

extern "C" void kernel_launch(void* const* d_in, const int* in_sizes, int n_in,
                              void* d_out, int out_size, void* d_ws, size_t ws_size,
                              hipStream_t stream) {
    const float* ie  = (const float*)d_in[0];   // [B,T,E]
    const float* yh  = (const float*)d_in[1];   // [B,T,1]
    const float* aW1 = (const float*)d_in[2];   // [768,256]
    const float* ab1 = (const float*)d_in[3];   // [256]
    const float* aW2 = (const float*)d_in[4];   // [256,1]
    // d_in[5] = ab2: additive constant inside softmax -> invariant, unused
    const float* Wih = (const float*)d_in[6];   // [1024,1]
    const float* Whh = (const float*)d_in[7];   // [1024,256]
    const float* bih = (const float*)d_in[8];   // [1024]
    const float* bhh = (const float*)d_in[9];   // [1024]
    const float* fcW = (const float*)d_in[10];  // [1,257]
    const float* fcb = (const float*)d_in[11];  // [1]
    const float* ffW = (const float*)d_in[12];  // [1,512]
    const float* ffb = (const float*)d_in[13];  // [1]
    float* out = (float*)d_out;

    // workspace layout
    _Float16* ep   = (_Float16*)d_ws;                        // 16,777,216 f16 = 32 MiB
    _Float16* aW1h = ep + (size_t)BB * TT * EE;              // 131072 f16
    _Float16* WhhH = aW1h + 512 * EE;                        // 262144 f16
    float* bias = (float*)(WhhH + 262144);                   // 1024 f32
    float* iefc = bias + 1024;                               // 65536 f32
    float* ieff = iefc + BB * TT;                            // 65536 f32

    k_pack<<<1540, 256, 0, stream>>>(aW1, Whh, bih, bhh, aW1h, WhhH, bias);
    k_encproj<<<2048, 256, 0, stream>>>(ie, aW1, fcW, ffW, ep, iefc, ieff);
    k_main<<<BB / NB, NTHR, 0, stream>>>(ep, yh, aW1h, WhhH, bias, ab1, aW2,
                                         Wih, fcW, fcb, ffW, ffb, iefc, ieff, out);
}